// Round 3
// baseline (200.312 us; speedup 1.0000x reference)
//
#include <hip/hip_runtime.h>
#include <hip/hip_bf16.h>
#include <stdint.h>

typedef __attribute__((ext_vector_type(8))) short short8;   // 8 bf16 (4 VGPRs) MFMA A/B frag
typedef __attribute__((ext_vector_type(4))) float f32x4;    // MFMA C/D frag

__device__ __forceinline__ float softplus_f(float x) {
    return (x > 0.f) ? (x + log1pf(expf(-x))) : log1pf(expf(x));
}

// mode 0: plain cast; mode 1: column-monotone (cols 0..3 -> +softplus, 4..7 -> -softplus, rest raw, 256 cols);
// mode 2: softplus everywhere
__global__ void xform_kernel(const float* __restrict__ src, __hip_bfloat16* __restrict__ dst,
                             int n4, int mode) {
    int i = blockIdx.x * blockDim.x + threadIdx.x;
    if (i >= n4) return;
    float4 v = reinterpret_cast<const float4*>(src)[i];
    float r[4] = {v.x, v.y, v.z, v.w};
    int base = i << 2;
#pragma unroll
    for (int j = 0; j < 4; ++j) {
        float x = r[j];
        float y = x;
        if (mode == 2) {
            y = softplus_f(x);
        } else if (mode == 1) {
            int col = (base + j) & 255;
            if (col < 8) {
                float s = softplus_f(x);
                y = (col < 4) ? s : -s;
            }
        }
        dst[base + j] = __float2bfloat16(y);
    }
}

#define GLOAD16(src, dst)                                                                  \
    __builtin_amdgcn_global_load_lds((const __attribute__((address_space(1))) void*)(src), \
                                     (__attribute__((address_space(3))) void*)(dst), 16, 0, 0)

// Fused ICNN layer. Tile BM=128 x BN=256, 8 waves (2M x 4N), per-wave 64x64 (acc[4][4]).
// BK=64, 3 LDS buffers (144KB), counted vmcnt(6) pipeline (T3+T4), one s_barrier per step,
// T2 XOR swizzle (pre-swizzled global source + swizzled ds_read), T5 setprio around MFMA.
// Step map (HAS_U): 0-3 xf@Wut^T (relu'd at step 3), 4-7 xc@Wc^T, 8-11 xf@Wu^T, 12-27 z@U^T.
template<bool HAS_U, bool WRITE_F32>
__global__ __launch_bounds__(512, 2)
void icnn_layer_kernel(const short* __restrict__ xc, const short* __restrict__ xf,
                       const short* __restrict__ zin,
                       const short* __restrict__ Wc, const short* __restrict__ Wu,
                       const short* __restrict__ Wut, const short* __restrict__ U,
                       const float* __restrict__ bc, const float* __restrict__ bu,
                       const float* __restrict__ but,
                       __hip_bfloat16* __restrict__ zout, float* __restrict__ fout)
{
    __shared__ short As[3][128 * 64];   // 16KB per buffer
    __shared__ short Bs[3][256 * 64];   // 32KB per buffer; total 144KB
    const int t = threadIdx.x;          // 0..511
    const int lane = t & 63;
    const int wid = t >> 6;             // 0..7
    const int wr = wid >> 2;            // 0..1 (64-row slice of 128)
    const int wc = wid & 3;             // 0..3 (64-col slice of 256)
    const int l15 = lane & 15, l4 = lane >> 4;
    const int swz = l15 & 7;            // == row&7 for every fragment row this lane reads
    const int brow = blockIdx.x * 128;
    const int bcol = blockIdx.y * 256;

    constexpr int NSTEP = HAS_U ? 28 : 12;

    f32x4 acc[4][4];
#pragma unroll
    for (int m = 0; m < 4; ++m)
#pragma unroll
        for (int n = 0; n < 4; ++n) acc[m][n] = (f32x4){0.f, 0.f, 0.f, 0.f};

    // hoisted u-path bias
    float bt[4];
#pragma unroll
    for (int n = 0; n < 4; ++n) bt[n] = but[bcol + wc * 64 + n * 16 + l15];

    // resolve operands for step s; ld given as shift (256 -> 8, 1024 -> 10)
    auto seg = [&](int s, const short*& A, int& lsa, const short*& B, int& lsb, int& k0) {
        if (s < 4)       { A = xf;  lsa = 8;  B = Wut; lsb = 8;  k0 = s * 64; }
        else if (s < 8)  { A = xc;  lsa = 8;  B = Wc;  lsb = 8;  k0 = (s - 4) * 64; }
        else if (s < 12) { A = xf;  lsa = 8;  B = Wu;  lsb = 8;  k0 = (s - 8) * 64; }
        else             { A = zin; lsa = 10; B = U;   lsb = 10; k0 = (s - 12) * 64; }
    };

    // stage tile for step s into buffer sel; LDS dest linear, source column-chunk XOR-swizzled
    auto stage = [&](int sel, int s) {
        const short *A, *B; int lsa, lsb, k0;
        seg(s, A, lsa, B, lsb, k0);
        short* Ad = &As[sel][0];
        short* Bd = &Bs[sel][0];
        // A tile: 128x64 = 1024 16B-chunks, 2 per thread
#pragma unroll
        for (int it = 0; it < 2; ++it) {
            int c = it * 512 + t;
            int row = c >> 3;                 // 8 chunks per 64-elem row
            int js = (c & 7) ^ (row & 7);     // inverse swizzle on source
            GLOAD16(A + (((size_t)(brow + row)) << lsa) + k0 + js * 8, Ad + c * 8);
        }
        // B tile: 256x64 = 2048 chunks, 4 per thread
#pragma unroll
        for (int it = 0; it < 4; ++it) {
            int c = it * 512 + t;
            int row = c >> 3;
            int js = (c & 7) ^ (row & 7);
            GLOAD16(B + (((size_t)(bcol + row)) << lsb) + k0 + js * 8, Bd + c * 8);
        }
    };

    auto compute = [&](int sel) {
        const short* Asel = &As[sel][0];
        const short* Bsel = &Bs[sel][0];
#pragma unroll
        for (int kk = 0; kk < 2; ++kk) {
            int joff = ((kk * 4 + l4) ^ swz) << 3;   // swizzled column offset (shorts)
            short8 a[4], b[4];
#pragma unroll
            for (int m = 0; m < 4; ++m) {
                int row = wr * 64 + m * 16 + l15;
                a[m] = *(const short8*)&Asel[(row << 6) + joff];
            }
#pragma unroll
            for (int n = 0; n < 4; ++n) {
                int row = wc * 64 + n * 16 + l15;
                b[n] = *(const short8*)&Bsel[(row << 6) + joff];
            }
            __builtin_amdgcn_s_setprio(1);
#pragma unroll
            for (int m = 0; m < 4; ++m)
#pragma unroll
                for (int n = 0; n < 4; ++n)
                    acc[m][n] = __builtin_amdgcn_mfma_f32_16x16x32_bf16(a[m], b[n], acc[m][n], 0, 0, 0);
            __builtin_amdgcn_s_setprio(0);
        }
    };

    // ---- prologue: 2 stages in flight (12 loads/thread) ----
    stage(0, 0);
    stage(1, 1);

    // ---- main loop: counted vmcnt, ONE barrier per step, loads never drained to 0 ----
    for (int s = 0; s < NSTEP - 1; ++s) {
        // wait until stage(s) has fully landed; stage(s+1)'s 6 loads stay in flight
        asm volatile("s_waitcnt vmcnt(6)" ::: "memory");
        __builtin_amdgcn_s_barrier();
        // buffer (s+2)%3 was last read at iter s-1 -> the barrier above protects the overwrite
        if (s + 2 < NSTEP) stage((s + 2) % 3, s + 2);
        compute(s % 3);
        if (s == 3) {
            // u = relu(xf@Wut^T + but); MFMA accumulates the remaining paths on top
#pragma unroll
            for (int n = 0; n < 4; ++n)
#pragma unroll
                for (int m = 0; m < 4; ++m)
#pragma unroll
                    for (int v = 0; v < 4; ++v)
                        acc[m][n][v] = fmaxf(acc[m][n][v] + bt[n], 0.f);
        }
    }
    // last step: drain remaining loads
    asm volatile("s_waitcnt vmcnt(0)" ::: "memory");
    __builtin_amdgcn_s_barrier();
    compute((NSTEP - 1) % 3);

    // ---- epilogue: + (bc + bu), relu, store ----
#pragma unroll
    for (int n = 0; n < 4; ++n) {
        int col = bcol + wc * 64 + n * 16 + l15;
        float bb = bc[col] + bu[col];
#pragma unroll
        for (int m = 0; m < 4; ++m) {
            int row = brow + wr * 64 + m * 16 + l4 * 4;
#pragma unroll
            for (int v = 0; v < 4; ++v) {
                float val = fmaxf(acc[m][n][v] + bb, 0.f);
                if constexpr (WRITE_F32) {
                    fout[(size_t)(row + v) * 1024 + col] = val;
                } else {
                    zout[(size_t)(row + v) * 1024 + col] = __float2bfloat16(val);
                }
            }
        }
    }
}

extern "C" void kernel_launch(void* const* d_in, const int* in_sizes, int n_in,
                              void* d_out, int out_size, void* d_ws, size_t ws_size,
                              hipStream_t stream)
{
    const float* xc    = (const float*)d_in[0];
    const float* xf    = (const float*)d_in[1];
    const float* Wc_w  = (const float*)d_in[2];
    const float* Wc_b  = (const float*)d_in[3];
    const float* Wu_w  = (const float*)d_in[4];
    const float* Wu_b  = (const float*)d_in[5];
    const float* Wut_w = (const float*)d_in[6];
    const float* Wut_b = (const float*)d_in[7];
    const float* raw_U = (const float*)d_in[8];

    // workspace layout (bf16 buffers), ~36 MB total
    short* p = (short*)d_ws;
    short* xc_bf  = p; p += 8192 * 256;
    short* xf_bf  = p; p += 8192 * 256;
    short* Wc_bf  = p; p += 4 * 1024 * 256;
    short* Wu_bf  = p; p += 4 * 1024 * 256;
    short* Wut_bf = p; p += 4 * 1024 * 256;
    short* U_bf   = p; p += 3 * 1024 * 1024;
    short* z_a    = p; p += 8192 * 1024;
    // z_b lives in d_out (bf16 scratch); layer 3 fully overwrites d_out with fp32 result.
    short* z_b = (short*)d_out;

    dim3 tb256(256);
    xform_kernel<<<dim3(2048), tb256, 0, stream>>>(xc,    (__hip_bfloat16*)xc_bf,  8192 * 256 / 4, 0);
    xform_kernel<<<dim3(2048), tb256, 0, stream>>>(xf,    (__hip_bfloat16*)xf_bf,  8192 * 256 / 4, 0);
    xform_kernel<<<dim3(1024), tb256, 0, stream>>>(Wc_w,  (__hip_bfloat16*)Wc_bf,  4 * 1024 * 256 / 4, 1);
    xform_kernel<<<dim3(1024), tb256, 0, stream>>>(Wu_w,  (__hip_bfloat16*)Wu_bf,  4 * 1024 * 256 / 4, 1);
    xform_kernel<<<dim3(1024), tb256, 0, stream>>>(Wut_w, (__hip_bfloat16*)Wut_bf, 4 * 1024 * 256 / 4, 1);
    xform_kernel<<<dim3(3072), tb256, 0, stream>>>(raw_U, (__hip_bfloat16*)U_bf,   3 * 1024 * 1024 / 4, 2);

    dim3 tb(512);
    dim3 grid(8192 / 128, 1024 / 256);   // 64 x 4 = 256 blocks = 1/CU
    const int WS = 1024 * 256;
    const int US = 1024 * 1024;

    // layer 0 (no recurrence) -> z_a
    icnn_layer_kernel<false, false><<<grid, tb, 0, stream>>>(
        xc_bf, xf_bf, nullptr, Wc_bf, Wu_bf, Wut_bf, nullptr,
        Wc_b, Wu_b, Wut_b, (__hip_bfloat16*)z_a, nullptr);
    // layer 1 -> z_b (in d_out)
    icnn_layer_kernel<true, false><<<grid, tb, 0, stream>>>(
        xc_bf, xf_bf, z_a, Wc_bf + WS, Wu_bf + WS, Wut_bf + WS, U_bf,
        Wc_b + 1024, Wu_b + 1024, Wut_b + 1024, (__hip_bfloat16*)z_b, nullptr);
    // layer 2 -> z_a
    icnn_layer_kernel<true, false><<<grid, tb, 0, stream>>>(
        xc_bf, xf_bf, z_b, Wc_bf + 2 * WS, Wu_bf + 2 * WS, Wut_bf + 2 * WS, U_bf + US,
        Wc_b + 2048, Wu_b + 2048, Wut_b + 2048, (__hip_bfloat16*)z_a, nullptr);
    // layer 3 -> fp32 d_out
    icnn_layer_kernel<true, true><<<grid, tb, 0, stream>>>(
        xc_bf, xf_bf, z_a, Wc_bf + 3 * WS, Wu_bf + 3 * WS, Wut_bf + 3 * WS, U_bf + 2 * US,
        Wc_b + 3072, Wu_b + 3072, Wut_b + 3072, nullptr, (float*)d_out);
}

// Round 4
// 176.312 us; speedup vs baseline: 1.1361x; 1.1361x over previous
//
#include <hip/hip_runtime.h>
#include <hip/hip_bf16.h>
#include <stdint.h>

typedef __attribute__((ext_vector_type(8))) short short8;   // 8 bf16 (4 VGPRs) MFMA A/B frag
typedef __attribute__((ext_vector_type(4))) float f32x4;    // MFMA C/D frag

__device__ __forceinline__ float softplus_f(float x) {
    return (x > 0.f) ? (x + log1pf(expf(-x))) : log1pf(expf(x));
}

// mode 0: plain cast; mode 1: column-monotone (cols 0..3 -> +softplus, 4..7 -> -softplus, rest raw, 256 cols);
// mode 2: softplus everywhere
__global__ void xform_kernel(const float* __restrict__ src, __hip_bfloat16* __restrict__ dst,
                             int n4, int mode) {
    int i = blockIdx.x * blockDim.x + threadIdx.x;
    if (i >= n4) return;
    float4 v = reinterpret_cast<const float4*>(src)[i];
    float r[4] = {v.x, v.y, v.z, v.w};
    int base = i << 2;
#pragma unroll
    for (int j = 0; j < 4; ++j) {
        float x = r[j];
        float y = x;
        if (mode == 2) {
            y = softplus_f(x);
        } else if (mode == 1) {
            int col = (base + j) & 255;
            if (col < 8) {
                float s = softplus_f(x);
                y = (col < 4) ? s : -s;
            }
        }
        dst[base + j] = __float2bfloat16(y);
    }
}

#define GLOAD16(src, dst)                                                                  \
    __builtin_amdgcn_global_load_lds((const __attribute__((address_space(1))) void*)(src), \
                                     (__attribute__((address_space(3))) void*)(dst), 16, 0, 0)

// Fused ICNN layer. Tile BM=128 x BN=256, 8 waves (2M x 4N), per-wave 64x64 (acc[4][4]).
// BK=64, 3 LDS buffers (144KB), counted vmcnt(6) pipeline, one s_barrier per step.
// KEY ORDERING (round-4 fix): per step, ds_read ALL fragments into registers FIRST,
// then issue next-next stage's global_load_lds, then MFMA. Any compiler-inserted
// conservative vmcnt wait before the ds_reads then only covers loads issued a full
// step earlier (cheap), instead of just-issued ones (full latency, the R3 bug).
// Step map (HAS_U): 0-3 xf@Wut^T (relu'd at step 3), 4-7 xc@Wc^T, 8-11 xf@Wu^T, 12-27 z@U^T.
template<bool HAS_U, bool WRITE_F32>
__global__ __launch_bounds__(512, 2)
void icnn_layer_kernel(const short* __restrict__ xc, const short* __restrict__ xf,
                       const short* __restrict__ zin,
                       const short* __restrict__ Wc, const short* __restrict__ Wu,
                       const short* __restrict__ Wut, const short* __restrict__ U,
                       const float* __restrict__ bc, const float* __restrict__ bu,
                       const float* __restrict__ but,
                       __hip_bfloat16* __restrict__ zout, float* __restrict__ fout)
{
    __shared__ short As[3][128 * 64];   // 16KB per buffer
    __shared__ short Bs[3][256 * 64];   // 32KB per buffer; total 144KB
    const int t = threadIdx.x;          // 0..511
    const int lane = t & 63;
    const int wid = t >> 6;             // 0..7
    const int wr = wid >> 2;            // 0..1 (64-row slice of 128)
    const int wc = wid & 3;             // 0..3 (64-col slice of 256)
    const int l15 = lane & 15, l4 = lane >> 4;
    const int swz = l15 & 7;            // == row&7 for every fragment row this lane reads
    const int brow = blockIdx.x * 128;
    const int bcol = blockIdx.y * 256;

    constexpr int NSTEP = HAS_U ? 28 : 12;

    f32x4 acc[4][4];
#pragma unroll
    for (int m = 0; m < 4; ++m)
#pragma unroll
        for (int n = 0; n < 4; ++n) acc[m][n] = (f32x4){0.f, 0.f, 0.f, 0.f};

    // hoisted u-path bias
    float bt[4];
#pragma unroll
    for (int n = 0; n < 4; ++n) bt[n] = but[bcol + wc * 64 + n * 16 + l15];

    // resolve operands for step s; ld given as shift (256 -> 8, 1024 -> 10)
    auto seg = [&](int s, const short*& A, int& lsa, const short*& B, int& lsb, int& k0) {
        if (s < 4)       { A = xf;  lsa = 8;  B = Wut; lsb = 8;  k0 = s * 64; }
        else if (s < 8)  { A = xc;  lsa = 8;  B = Wc;  lsb = 8;  k0 = (s - 4) * 64; }
        else if (s < 12) { A = xf;  lsa = 8;  B = Wu;  lsb = 8;  k0 = (s - 8) * 64; }
        else             { A = zin; lsa = 10; B = U;   lsb = 10; k0 = (s - 12) * 64; }
    };

    // stage tile for step s into buffer sel; LDS dest linear, source column-chunk XOR-swizzled
    auto stage = [&](int sel, int s) {
        const short *A, *B; int lsa, lsb, k0;
        seg(s, A, lsa, B, lsb, k0);
        short* Ad = &As[sel][0];
        short* Bd = &Bs[sel][0];
        // A tile: 128x64 = 1024 16B-chunks, 2 per thread
#pragma unroll
        for (int it = 0; it < 2; ++it) {
            int c = it * 512 + t;
            int row = c >> 3;                 // 8 chunks per 64-elem row
            int js = (c & 7) ^ (row & 7);     // inverse swizzle on source
            GLOAD16(A + (((size_t)(brow + row)) << lsa) + k0 + js * 8, Ad + c * 8);
        }
        // B tile: 256x64 = 2048 chunks, 4 per thread
#pragma unroll
        for (int it = 0; it < 4; ++it) {
            int c = it * 512 + t;
            int row = c >> 3;
            int js = (c & 7) ^ (row & 7);
            GLOAD16(B + (((size_t)(bcol + row)) << lsb) + k0 + js * 8, Bd + c * 8);
        }
    };

    // ---- prologue: 2 stages in flight (12 loads/thread) ----
    stage(0, 0);
    stage(1, 1);

    // ---- main loop: ONE barrier per step; frag-reads BEFORE next stage issue ----
    for (int s = 0; s < NSTEP; ++s) {
        if (s == NSTEP - 1) {
            asm volatile("s_waitcnt vmcnt(0)" ::: "memory");
        } else {
            // stage(s) fully landed once outstanding <= 6 (only stage(s+1) remains in flight)
            asm volatile("s_waitcnt vmcnt(6)" ::: "memory");
        }
        __builtin_amdgcn_s_barrier();

        const int sel = s % 3;
        const short* Asel = &As[sel][0];
        const short* Bsel = &Bs[sel][0];

        // read ALL 16 fragments for this step into registers (static indexing)
        short8 a[2][4], b[2][4];
#pragma unroll
        for (int kk = 0; kk < 2; ++kk) {
            int joff = ((kk * 4 + l4) ^ swz) << 3;   // swizzled column offset (shorts)
#pragma unroll
            for (int m = 0; m < 4; ++m)
                a[kk][m] = *(const short8*)&Asel[((wr * 64 + m * 16 + l15) << 6) + joff];
#pragma unroll
            for (int n = 0; n < 4; ++n)
                b[kk][n] = *(const short8*)&Bsel[((wc * 64 + n * 16 + l15) << 6) + joff];
        }

        // issue next-next tile's DMA AFTER the reads; it has ~2 full steps to land
        if (s + 2 < NSTEP) stage((s + 2) % 3, s + 2);
        __builtin_amdgcn_sched_barrier(0);   // pin DMA issue before the MFMA cluster

        __builtin_amdgcn_s_setprio(1);
#pragma unroll
        for (int kk = 0; kk < 2; ++kk)
#pragma unroll
            for (int m = 0; m < 4; ++m)
#pragma unroll
                for (int n = 0; n < 4; ++n)
                    acc[m][n] = __builtin_amdgcn_mfma_f32_16x16x32_bf16(a[kk][m], b[kk][n], acc[m][n], 0, 0, 0);
        __builtin_amdgcn_s_setprio(0);

        if (s == 3) {
            // u = relu(xf@Wut^T + but); MFMA accumulates the remaining paths on top
#pragma unroll
            for (int n = 0; n < 4; ++n)
#pragma unroll
                for (int m = 0; m < 4; ++m)
#pragma unroll
                    for (int v = 0; v < 4; ++v)
                        acc[m][n][v] = fmaxf(acc[m][n][v] + bt[n], 0.f);
        }
    }

    // ---- epilogue: + (bc + bu), relu, store ----
#pragma unroll
    for (int n = 0; n < 4; ++n) {
        int col = bcol + wc * 64 + n * 16 + l15;
        float bb = bc[col] + bu[col];
#pragma unroll
        for (int m = 0; m < 4; ++m) {
            int row = brow + wr * 64 + m * 16 + l4 * 4;
#pragma unroll
            for (int v = 0; v < 4; ++v) {
                float val = fmaxf(acc[m][n][v] + bb, 0.f);
                if constexpr (WRITE_F32) {
                    fout[(size_t)(row + v) * 1024 + col] = val;
                } else {
                    zout[(size_t)(row + v) * 1024 + col] = __float2bfloat16(val);
                }
            }
        }
    }
}

extern "C" void kernel_launch(void* const* d_in, const int* in_sizes, int n_in,
                              void* d_out, int out_size, void* d_ws, size_t ws_size,
                              hipStream_t stream)
{
    const float* xc    = (const float*)d_in[0];
    const float* xf    = (const float*)d_in[1];
    const float* Wc_w  = (const float*)d_in[2];
    const float* Wc_b  = (const float*)d_in[3];
    const float* Wu_w  = (const float*)d_in[4];
    const float* Wu_b  = (const float*)d_in[5];
    const float* Wut_w = (const float*)d_in[6];
    const float* Wut_b = (const float*)d_in[7];
    const float* raw_U = (const float*)d_in[8];

    // workspace layout (bf16 buffers), ~36 MB total
    short* p = (short*)d_ws;
    short* xc_bf  = p; p += 8192 * 256;
    short* xf_bf  = p; p += 8192 * 256;
    short* Wc_bf  = p; p += 4 * 1024 * 256;
    short* Wu_bf  = p; p += 4 * 1024 * 256;
    short* Wut_bf = p; p += 4 * 1024 * 256;
    short* U_bf   = p; p += 3 * 1024 * 1024;
    short* z_a    = p; p += 8192 * 1024;
    // z_b lives in d_out (bf16 scratch); layer 3 fully overwrites d_out with fp32 result.
    short* z_b = (short*)d_out;

    dim3 tb256(256);
    xform_kernel<<<dim3(2048), tb256, 0, stream>>>(xc,    (__hip_bfloat16*)xc_bf,  8192 * 256 / 4, 0);
    xform_kernel<<<dim3(2048), tb256, 0, stream>>>(xf,    (__hip_bfloat16*)xf_bf,  8192 * 256 / 4, 0);
    xform_kernel<<<dim3(1024), tb256, 0, stream>>>(Wc_w,  (__hip_bfloat16*)Wc_bf,  4 * 1024 * 256 / 4, 1);
    xform_kernel<<<dim3(1024), tb256, 0, stream>>>(Wu_w,  (__hip_bfloat16*)Wu_bf,  4 * 1024 * 256 / 4, 1);
    xform_kernel<<<dim3(1024), tb256, 0, stream>>>(Wut_w, (__hip_bfloat16*)Wut_bf, 4 * 1024 * 256 / 4, 1);
    xform_kernel<<<dim3(3072), tb256, 0, stream>>>(raw_U, (__hip_bfloat16*)U_bf,   3 * 1024 * 1024 / 4, 2);

    dim3 tb(512);
    dim3 grid(8192 / 128, 1024 / 256);   // 64 x 4 = 256 blocks = 1/CU
    const int WS = 1024 * 256;
    const int US = 1024 * 1024;

    // layer 0 (no recurrence) -> z_a
    icnn_layer_kernel<false, false><<<grid, tb, 0, stream>>>(
        xc_bf, xf_bf, nullptr, Wc_bf, Wu_bf, Wut_bf, nullptr,
        Wc_b, Wu_b, Wut_b, (__hip_bfloat16*)z_a, nullptr);
    // layer 1 -> z_b (in d_out)
    icnn_layer_kernel<true, false><<<grid, tb, 0, stream>>>(
        xc_bf, xf_bf, z_a, Wc_bf + WS, Wu_bf + WS, Wut_bf + WS, U_bf,
        Wc_b + 1024, Wu_b + 1024, Wut_b + 1024, (__hip_bfloat16*)z_b, nullptr);
    // layer 2 -> z_a
    icnn_layer_kernel<true, false><<<grid, tb, 0, stream>>>(
        xc_bf, xf_bf, z_b, Wc_bf + 2 * WS, Wu_bf + 2 * WS, Wut_bf + 2 * WS, U_bf + US,
        Wc_b + 2048, Wu_b + 2048, Wut_b + 2048, (__hip_bfloat16*)z_a, nullptr);
    // layer 3 -> fp32 d_out
    icnn_layer_kernel<true, true><<<grid, tb, 0, stream>>>(
        xc_bf, xf_bf, z_a, Wc_bf + 3 * WS, Wu_bf + 3 * WS, Wut_bf + 3 * WS, U_bf + 2 * US,
        Wc_b + 3072, Wu_b + 3072, Wut_b + 3072, nullptr, (float*)d_out);
}